// Round 16
// baseline (438.593 us; speedup 1.0000x reference)
//
#include <hip/hip_runtime.h>
#include <math.h>
#include <stdint.h>

#define B_PTS   262144
#define NLEV    16
#define MASK4   ((1u << 22) - 1u)
#define MASK3   ((1u << 15) - 1u)
#define P1      2654435761u
#define P2      805459861u
#define P3      3674653429u

#define LSH     4                // first XCD-sharded level
#define NSHL    (NLEV - LSH)     // 12 sharded levels
#define NCHUNK  256              // point chunks per level (1024 pts/chunk)

typedef float f32x4 __attribute__((ext_vector_type(4)));

struct LevelParams {
    float res[NLEV];
    float rest[NLEV];
};

struct PtState {
    uint32_t a;                          // bl0 * PRIMES[0](=1), <= 513 < 2^19
    uint32_t t1e, t1o, t2e, t2o, t3e, t3o;
    float w0, w1, w2, w3;
};

// Fast-math state: no divisions. bl = floor(xc*res), w = x*res - bl.
// ULP-edge cell flips are harmless: the interpolant is continuous across the
// cell boundary (shared lattice corner, same hash) -> error ~1e-11 vs 2e-2.
__device__ __forceinline__ PtState mk_fast(float xx, float xy, float xz, float xw,
                                           float R, float Rt)
{
    PtState st;
    const float xd[4] = { xx, xy, xz, xw };
    const float rv[4] = { R, R, R, Rt };
    uint32_t tt[4][2]; float ww[4];
    #pragma unroll
    for (int d = 0; d < 4; ++d) {
        float xc = fminf(fmaxf(xd[d], 0.0f), 1.0f);
        float bl = floorf(xc * rv[d]);
        float w  = fmaf(xd[d], rv[d], -bl);
        uint32_t bi = (uint32_t)(int)bl;
        uint32_t prime = (d == 0) ? 1u : (d == 1) ? P1 : (d == 2) ? P2 : P3;
        tt[d][0] = bi * prime;
        tt[d][1] = tt[d][0] + prime;
        ww[d] = w;
    }
    st.a   = tt[0][0];
    st.t1e = tt[1][0]; st.t1o = tt[1][1];
    st.t2e = tt[2][0]; st.t2o = tt[2][1];
    st.t3e = tt[3][0]; st.t3o = tt[3][1];
    st.w0 = ww[0]; st.w1 = ww[1]; st.w2 = ww[2]; st.w3 = ww[3];
    return st;
}

// round-to-nearest f32 -> bf16 (tolerance 2e-2 vs values ~1e-4: err ~1e-7)
__device__ __forceinline__ uint32_t bfr(float v) {
    uint32_t u = __float_as_uint(v);
    u += 0x7FFFu + ((u >> 16) & 1u);
    return u >> 16;
}

// In-flight gather window for one point: 16 asm-issued 8B loads whose result
// registers are FORCED live (the R10/R12 failure mode was the register
// allocator silently shrinking the window: VGPR 52/72 < the ~120 needed).
struct Gather {
    float2 v[16];      // corner values (dummy-loaded if pair inactive)
    float  wc[8];      // (j,k,l) weights, pre-zeroed when pair inactive
    float  wx0, wx1;   // dim-0 lerp weights
};

// Issue one point's 16 gathers via inline asm (SADDR + 32-bit voffset).
// asm volatile keeps issue order and prevents the scheduler from sinking
// loads toward uses. Inactive pairs load a fixed slice-base line (L1-hot).
__device__ __forceinline__ void issue_g(const float2* __restrict__ tab4,
                                        const PtState& st, uint32_t sh,
                                        Gather& g)
{
    const float w1e = 1.0f - st.w1, w2e = 1.0f - st.w2, w3e = 1.0f - st.w3;
    const float q00 = w1e * w2e, q01 = w1e * st.w2,
                q10 = st.w1 * w2e, q11 = st.w1 * st.w2;
    const float wcv[8] = { q00 * w3e, q00 * st.w3, q01 * w3e, q01 * st.w3,
                           q10 * w3e, q10 * st.w3, q11 * w3e, q11 * st.w3 };
    g.wx0 = 1.0f - st.w0; g.wx1 = st.w0;
    const uint32_t a0 = st.a, a1 = a0 + 1u;
    const uint32_t dummy_off = (sh << 19) * 8u;

    #pragma unroll
    for (int pp = 0; pp < 8; ++pp) {       // pp bits: 2=j, 1=k, 0=l
        uint32_t E = (((pp & 4) ? st.t1o : st.t1e) ^
                      ((pp & 2) ? st.t2o : st.t2e) ^
                      ((pp & 1) ? st.t3o : st.t3e)) & MASK4;
        const bool act = (E >> 19) == sh;  // pair-level: a < 2^19
        // a <= 513 flips only low bits: E^a stays inside the slice
        uint32_t off0 = act ? (E ^ a0) * 8u : dummy_off;
        uint32_t off1 = act ? (E ^ a1) * 8u : dummy_off;
        asm volatile("global_load_dwordx2 %0, %1, %2"
                     : "=v"(g.v[2 * pp]) : "v"(off0), "s"(tab4));
        asm volatile("global_load_dwordx2 %0, %1, %2"
                     : "=v"(g.v[2 * pp + 1]) : "v"(off1), "s"(tab4));
        g.wc[pp] = act ? wcv[pp] : 0.0f;
    }
}

__device__ __forceinline__ uint32_t consume_g(const Gather& g)
{
    float ex = 0.0f, ey = 0.0f;
    #pragma unroll
    for (int pp = 0; pp < 8; ++pp) {
        float u0 = g.wc[pp] * g.wx0, u1 = g.wc[pp] * g.wx1;
        ex = fmaf(g.v[2 * pp].x, u0, fmaf(g.v[2 * pp + 1].x, u1, ex));
        ey = fmaf(g.v[2 * pp].y, u0, fmaf(g.v[2 * pp + 1].y, u1, ey));
    }
    return bfr(ex) | (bfr(ey) << 16);
}

// counted waitcnt + scheduling fence (guide rule #18: hipcc hoists
// register-only consumers past inline-asm waitcnt without the fence)
#define VMWAIT(N) do {                                            \
    asm volatile("s_waitcnt vmcnt(" #N ")" ::: "memory");         \
    __builtin_amdgcn_sched_barrier(0);                            \
} while (0)

// ---------------- K_shard: 4D levels LSH..15, XCD-sharded hash space --------
// bid = ((levi*NCHUNK + chunk)*8 + s): round-robin dispatch puts all blocks of
// shard s on XCD s; the 4.19 MB table slice stays L2-resident.
// 2-deep asm pipeline with counted vmcnt(16): 32 loads in flight per wave in
// steady state (vs ~4 when the compiler schedules). Stores deferred to the
// end so vmcnt counts stay exact (stores share the counter).
__global__ __launch_bounds__(256, 2)
void k_shard(const float4* __restrict__ x,
             const float2* __restrict__ emb4d,
             uint32_t* __restrict__ ws2, LevelParams lp)
{
    const int bid   = blockIdx.x;
    const int s     = bid & 7;
    const int rest  = bid >> 3;
    const int chunk = rest & (NCHUNK - 1);
    const int levi  = rest >> 8;           // log2(NCHUNK) = 8
    const int lev   = LSH + levi;
    const uint32_t sh = (uint32_t)s;

    const float2* tab4 = emb4d + ((size_t)lev << 22);
    const float R = lp.res[lev], Rt = lp.rest[lev];
    const int pbase = chunk * 1024 + threadIdx.x;
    uint32_t* dst = ws2 + (size_t)(levi * 8 + s) * B_PTS + pbase;

    f32x4 x0 = *reinterpret_cast<const f32x4*>(&x[pbase]);
    f32x4 x1 = *reinterpret_cast<const f32x4*>(&x[pbase + 256]);
    f32x4 x2 = *reinterpret_cast<const f32x4*>(&x[pbase + 512]);
    f32x4 x3 = *reinterpret_cast<const f32x4*>(&x[pbase + 768]);
    // materialize x and drain the compiler's loads BEFORE any asm gather --
    // otherwise the compiler's own conservative vmcnt waits (it can't see our
    // asm loads) would drain the pipeline mid-loop.
    asm volatile("" : "+v"(x0), "+v"(x1), "+v"(x2), "+v"(x3));
    asm volatile("s_waitcnt vmcnt(0)" ::: "memory");

    Gather A, B;
    PtState st;

    st = mk_fast(x0.x, x0.y, x0.z, x0.w, R, Rt);
    issue_g(tab4, st, sh, A);                       // 16 in flight
    st = mk_fast(x1.x, x1.y, x1.z, x1.w, R, Rt);
    issue_g(tab4, st, sh, B);                       // 32 in flight
    VMWAIT(16);                                     // A landed, B in flight
    uint32_t pk0 = consume_g(A);
    st = mk_fast(x2.x, x2.y, x2.z, x2.w, R, Rt);
    issue_g(tab4, st, sh, A);
    VMWAIT(16);                                     // B landed, A' in flight
    uint32_t pk1 = consume_g(B);
    st = mk_fast(x3.x, x3.y, x3.z, x3.w, R, Rt);
    issue_g(tab4, st, sh, B);
    VMWAIT(16);                                     // A' landed
    uint32_t pk2 = consume_g(A);
    VMWAIT(0);                                      // B' landed
    uint32_t pk3 = consume_g(B);

    __builtin_nontemporal_store(pk0, dst);
    __builtin_nontemporal_store(pk1, dst + 256);
    __builtin_nontemporal_store(pk2, dst + 512);
    __builtin_nontemporal_store(pk3, dst + 768);
}

// ---------------- K_final: 3D + 4D levels 0..3 + shard reduce ---------------
// grid.y = 4: block handles levels 4y..4y+3. Even-pair merge on 3D and
// low-4D gathers.
__global__ __launch_bounds__(256)
void k_final(const float4* __restrict__ x,
             const float2* __restrict__ emb4d,
             const float2* __restrict__ emb3d,
             const uint32_t* __restrict__ ws2,
             float* __restrict__ out, float* __restrict__ keep,
             LevelParams lp)
{
    __shared__ float tile[256 * 9];
    const int t    = threadIdx.x;
    const int p    = blockIdx.x * 256 + t;
    const int lev0 = blockIdx.y * 4;

    const float4 xv = x[p];

    #pragma unroll
    for (int l4 = 0; l4 < 4; ++l4) {
        const int lev = lev0 + l4;
        PtState st = mk_fast(xv.x, xv.y, xv.z, xv.w, lp.res[lev], lp.rest[lev]);
        const uint32_t a0 = st.a, a1 = st.a + 1u;
        const bool odd = (a0 & 1u) != 0u;
        const float wx0 = 1.0f - st.w0, wx1 = st.w0;
        const float wy[2] = { 1.0f - st.w1, st.w1 };
        const float wz[2] = { 1.0f - st.w2, st.w2 };
        const float wwv[2] = { 1.0f - st.w3, st.w3 };

        float ex = 0.0f, ey = 0.0f;

        // shard partials for this level (coalesced u32 reads, bf16x2 packed)
        if (lev >= LSH) {
            const int li = lev - LSH;
            #pragma unroll
            for (int s2 = 0; s2 < 8; ++s2) {
                uint32_t w = ws2[(size_t)(li * 8 + s2) * B_PTS + p];
                ex += __uint_as_float(w << 16);
                ey += __uint_as_float(w & 0xFFFF0000u);
            }
        }

        // 3D: 4 (j,k) pairs, even-merged (footprint <=256 KB, cache-resident)
        {
            const float2* tab3 = emb3d + ((size_t)lev << 15);
            #pragma unroll
            for (int pp = 0; pp < 4; ++pp) {  // pp bits: 1=j, 0=k
                uint32_t E = (((pp & 2) ? st.t1o : st.t1e) ^
                              ((pp & 1) ? st.t2o : st.t2e)) & MASK3;
                uint32_t h0 = E ^ a0;
                float4 qq = *reinterpret_cast<const float4*>(tab3 + (h0 & ~1u));
                float2 ee = make_float2(0.0f, 0.0f);
                if (odd) ee = tab3[E ^ a1];
                const bool hi = (h0 & 1u) != 0u;
                float c0x = hi ? qq.z : qq.x, c0y = hi ? qq.w : qq.y;
                float c1x = odd ? ee.x : (hi ? qq.x : qq.z);
                float c1y = odd ? ee.y : (hi ? qq.y : qq.w);
                float wp = wy[(pp >> 1) & 1] * wz[pp & 1];
                ex = fmaf(c0x, wp * wx0, fmaf(c1x, wp * wx1, ex));
                ey = fmaf(c0y, wp * wx0, fmaf(c1y, wp * wx1, ey));
            }
        }

        // 4D levels 0..3: even-merged, touched footprints <=22 MB (L3)
        if (lev < LSH) {
            const float2* tab4 = emb4d + ((size_t)lev << 22);
            #pragma unroll
            for (int pp = 0; pp < 8; ++pp) {  // pp bits: 2=j, 1=k, 0=l
                uint32_t E = (((pp & 4) ? st.t1o : st.t1e) ^
                              ((pp & 2) ? st.t2o : st.t2e) ^
                              ((pp & 1) ? st.t3o : st.t3e)) & MASK4;
                uint32_t h0 = E ^ a0;
                float4 qq = *reinterpret_cast<const float4*>(tab4 + (h0 & ~1u));
                float2 ee = make_float2(0.0f, 0.0f);
                if (odd) ee = tab4[E ^ a1];
                const bool hi = (h0 & 1u) != 0u;
                float c0x = hi ? qq.z : qq.x, c0y = hi ? qq.w : qq.y;
                float c1x = odd ? ee.x : (hi ? qq.x : qq.z);
                float c1y = odd ? ee.y : (hi ? qq.y : qq.w);
                float wp = wy[(pp >> 2) & 1] * wz[(pp >> 1) & 1] * wwv[pp & 1];
                ex = fmaf(c0x, wp * wx0, fmaf(c1x, wp * wx1, ex));
                ey = fmaf(c0y, wp * wx0, fmaf(c1y, wp * wx1, ey));
            }
        }

        tile[t * 9 + 2 * l4]     = ex;
        tile[t * 9 + 2 * l4 + 1] = ey;
    }

    __syncthreads();

    // write 8 columns per point (32B chunks)
    float* ob = out + (size_t)blockIdx.x * (256 * 32) + lev0 * 2;
    #pragma unroll
    for (int k = 0; k < 8; ++k) {
        int idx = k * 256 + t;
        int row = idx >> 3, col = idx & 7;
        ob[(size_t)row * 32 + col] = tile[row * 9 + col];
    }

    if (blockIdx.y == 0) {
        bool k4 = (xv.x >= 0.0f) && (xv.x <= 1.0f) &&
                  (xv.y >= 0.0f) && (xv.y <= 1.0f) &&
                  (xv.z >= 0.0f) && (xv.z <= 1.0f) &&
                  (xv.w >= 0.0f) && (xv.w <= 1.0f);
        keep[p] = k4 ? 1.0f : 0.0f;
    }
}

// ---------------- fallback (monolithic) if ws is too small ------------------
__global__ __launch_bounds__(256)
void embed_all(const float4* __restrict__ x,
               const float2* __restrict__ emb4d,
               const float2* __restrict__ emb3d,
               float* __restrict__ out,
               float* __restrict__ keep,
               LevelParams lp)
{
    __shared__ float tile[16 * 33];
    const int t = threadIdx.x;
    const int pl = t & 15;
    const int lev = t >> 4;
    const int pbase = blockIdx.x * 16;

    const float4 xv = x[pbase + pl];
    PtState st = mk_fast(xv.x, xv.y, xv.z, xv.w, lp.res[lev], lp.rest[lev]);
    const uint32_t a0 = st.a, a1 = st.a + 1u;
    const float wx[2] = { 1.0f - st.w0, st.w0 };
    const float wy[2] = { 1.0f - st.w1, st.w1 };
    const float wz[2] = { 1.0f - st.w2, st.w2 };
    const float wwv[2] = { 1.0f - st.w3, st.w3 };
    float ex = 0.0f, ey = 0.0f;

    const float2* tab4 = emb4d + ((size_t)lev << 22);
    #pragma unroll
    for (int c = 0; c < 16; ++c) {
        uint32_t E = ((c & 4) ? st.t1o : st.t1e) ^ ((c & 2) ? st.t2o : st.t2e) ^
                     ((c & 1) ? st.t3o : st.t3e);
        uint32_t h = (E ^ ((c & 8) ? a1 : a0)) & MASK4;
        float wt = wx[(c >> 3) & 1] * wy[(c >> 2) & 1] *
                   wz[(c >> 1) & 1] * wwv[c & 1];
        float2 v = tab4[h];
        ex = fmaf(v.x, wt, ex);
        ey = fmaf(v.y, wt, ey);
    }
    const float2* tab3 = emb3d + ((size_t)lev << 15);
    #pragma unroll
    for (int c = 0; c < 8; ++c) {
        uint32_t E = ((c & 2) ? st.t1o : st.t1e) ^ ((c & 1) ? st.t2o : st.t2e);
        uint32_t h = (E ^ ((c & 4) ? a1 : a0)) & MASK3;
        float wt = wx[(c >> 2) & 1] * wy[(c >> 1) & 1] * wz[c & 1];
        float2 v = tab3[h];
        ex = fmaf(v.x, wt, ex);
        ey = fmaf(v.y, wt, ey);
    }

    tile[pl * 33 + 2 * lev]     = ex;
    tile[pl * 33 + 2 * lev + 1] = ey;
    __syncthreads();
    {
        int pw = t >> 4;
        int cw = (2 * t) & 31;
        float2 v = make_float2(tile[pw * 33 + cw], tile[pw * 33 + cw + 1]);
        *reinterpret_cast<float2*>(out + (size_t)pbase * 32 + 2 * t) = v;
    }
    if (t < 16) {
        const float4 xk = x[pbase + t];
        bool k4 = (xk.x >= 0.0f) && (xk.x <= 1.0f) &&
                  (xk.y >= 0.0f) && (xk.y <= 1.0f) &&
                  (xk.z >= 0.0f) && (xk.z <= 1.0f) &&
                  (xk.w >= 0.0f) && (xk.w <= 1.0f);
        keep[pbase + t] = k4 ? 1.0f : 0.0f;
    }
}

extern "C" void kernel_launch(void* const* d_in, const int* in_sizes, int n_in,
                              void* d_out, int out_size, void* d_ws, size_t ws_size,
                              hipStream_t stream)
{
    const float4* x     = (const float4*)d_in[0];
    const float2* emb4d = (const float2*)d_in[1];
    const float2* emb3d = (const float2*)d_in[2];
    float* out  = (float*)d_out;
    float* keep = out + (size_t)B_PTS * 32;

    // Replicate numpy's double-precision level-resolution computation exactly.
    LevelParams lp;
    const double b  = exp((log(512.0) - log(16.0)) / 15.0);
    const double bt = exp((log(32.0)  - log(2.0))  / 15.0);
    for (int i = 0; i < NLEV; ++i) {
        lp.res[i]  = (float)floor(16.0 * pow(b,  (double)i));
        lp.rest[i] = (float)floor(2.0  * pow(bt, (double)i));
    }

    const size_t ws2_bytes = (size_t)NSHL * 8 * B_PTS * 4;      // ~101 MB

    if (ws_size >= ws2_bytes && d_ws != nullptr) {
        uint32_t* ws2 = (uint32_t*)d_ws;
        k_shard<<<NSHL * NCHUNK * 8,    256, 0, stream>>>(x, emb4d, ws2, lp);
        k_final<<<dim3(B_PTS / 256, 4), 256, 0, stream>>>(x, emb4d, emb3d,
                                                          ws2, out, keep, lp);
    } else {
        embed_all<<<B_PTS / 16, 256, 0, stream>>>(x, emb4d, emb3d, out, keep, lp);
    }
}

// Round 17
// 438.458 us; speedup vs baseline: 1.0003x; 1.0003x over previous
//
#include <hip/hip_runtime.h>
#include <math.h>
#include <stdint.h>

#define B_PTS   262144
#define NLEV    16
#define MASK4   ((1u << 22) - 1u)
#define MASK3   ((1u << 15) - 1u)
#define P1      2654435761u
#define P2      805459861u
#define P3      3674653429u

#define LSH     4                // first XCD-sharded level
#define NSHL    (NLEV - LSH)     // 12 sharded levels
#define NCHUNK  256              // point chunks per level (1024 pts/chunk)

typedef float f32x4 __attribute__((ext_vector_type(4)));

struct LevelParams {
    float res[NLEV];
    float rest[NLEV];
};

struct PtState {
    uint32_t a;                          // bl0 * PRIMES[0](=1), <= 513 < 2^19
    uint32_t t1e, t1o, t2e, t2o, t3e, t3o;
    float w0, w1, w2, w3;
};

// Fast-math state: no divisions. bl = floor(xc*res), w = x*res - bl.
// ULP-edge cell flips are harmless: the interpolant is continuous across the
// cell boundary (shared lattice corner, same hash) -> error ~1e-11 vs 2e-2.
__device__ __forceinline__ PtState mk_fast(float xx, float xy, float xz, float xw,
                                           float R, float Rt)
{
    PtState st;
    const float xd[4] = { xx, xy, xz, xw };
    const float rv[4] = { R, R, R, Rt };
    uint32_t tt[4][2]; float ww[4];
    #pragma unroll
    for (int d = 0; d < 4; ++d) {
        float xc = fminf(fmaxf(xd[d], 0.0f), 1.0f);
        float bl = floorf(xc * rv[d]);
        float w  = fmaf(xd[d], rv[d], -bl);
        uint32_t bi = (uint32_t)(int)bl;
        uint32_t prime = (d == 0) ? 1u : (d == 1) ? P1 : (d == 2) ? P2 : P3;
        tt[d][0] = bi * prime;
        tt[d][1] = tt[d][0] + prime;
        ww[d] = w;
    }
    st.a   = tt[0][0];
    st.t1e = tt[1][0]; st.t1o = tt[1][1];
    st.t2e = tt[2][0]; st.t2o = tt[2][1];
    st.t3e = tt[3][0]; st.t3o = tt[3][1];
    st.w0 = ww[0]; st.w1 = ww[1]; st.w2 = ww[2]; st.w3 = ww[3];
    return st;
}

// round-to-nearest f32 -> bf16 (tolerance 2e-2 vs values ~1e-4: err ~1e-7)
__device__ __forceinline__ uint32_t bfr(float v) {
    uint32_t u = __float_as_uint(v);
    u += 0x7FFFu + ((u >> 16) & 1u);
    return u >> 16;
}

// In-flight gather window for one point: 16 asm-issued 8B loads whose result
// registers are FORCED live (the R10/R12 failure mode was the register
// allocator silently shrinking the window: VGPR 52/72 < the ~120 needed).
struct Gather {
    float2 v[16];      // corner values (dummy-loaded if pair inactive)
    float  wc[8];      // (j,k,l) weights, pre-zeroed when pair inactive
    float  wx0, wx1;   // dim-0 lerp weights
};

// Issue one point's 16 gathers via inline asm (SADDR + 32-bit voffset).
// asm volatile keeps issue order and prevents the scheduler from sinking
// loads toward uses. Inactive pairs load a fixed slice-base line (L1-hot).
__device__ __forceinline__ void issue_g(const float2* __restrict__ tab4,
                                        const PtState& st, uint32_t sh,
                                        Gather& g)
{
    const float w1e = 1.0f - st.w1, w2e = 1.0f - st.w2, w3e = 1.0f - st.w3;
    const float q00 = w1e * w2e, q01 = w1e * st.w2,
                q10 = st.w1 * w2e, q11 = st.w1 * st.w2;
    const float wcv[8] = { q00 * w3e, q00 * st.w3, q01 * w3e, q01 * st.w3,
                           q10 * w3e, q10 * st.w3, q11 * w3e, q11 * st.w3 };
    g.wx0 = 1.0f - st.w0; g.wx1 = st.w0;
    const uint32_t a0 = st.a, a1 = a0 + 1u;
    const uint32_t dummy_off = (sh << 19) * 8u;

    #pragma unroll
    for (int pp = 0; pp < 8; ++pp) {       // pp bits: 2=j, 1=k, 0=l
        uint32_t E = (((pp & 4) ? st.t1o : st.t1e) ^
                      ((pp & 2) ? st.t2o : st.t2e) ^
                      ((pp & 1) ? st.t3o : st.t3e)) & MASK4;
        const bool act = (E >> 19) == sh;  // pair-level: a < 2^19
        // a <= 513 flips only low bits: E^a stays inside the slice
        uint32_t off0 = act ? (E ^ a0) * 8u : dummy_off;
        uint32_t off1 = act ? (E ^ a1) * 8u : dummy_off;
        asm volatile("global_load_dwordx2 %0, %1, %2"
                     : "=v"(g.v[2 * pp]) : "v"(off0), "s"(tab4));
        asm volatile("global_load_dwordx2 %0, %1, %2"
                     : "=v"(g.v[2 * pp + 1]) : "v"(off1), "s"(tab4));
        g.wc[pp] = act ? wcv[pp] : 0.0f;
    }
}

__device__ __forceinline__ uint32_t consume_g(const Gather& g)
{
    float ex = 0.0f, ey = 0.0f;
    #pragma unroll
    for (int pp = 0; pp < 8; ++pp) {
        float u0 = g.wc[pp] * g.wx0, u1 = g.wc[pp] * g.wx1;
        ex = fmaf(g.v[2 * pp].x, u0, fmaf(g.v[2 * pp + 1].x, u1, ex));
        ey = fmaf(g.v[2 * pp].y, u0, fmaf(g.v[2 * pp + 1].y, u1, ey));
    }
    return bfr(ex) | (bfr(ey) << 16);
}

// counted waitcnt + scheduling fence (guide rule #18: hipcc hoists
// register-only consumers past inline-asm waitcnt without the fence)
#define VMWAIT(N) do {                                            \
    asm volatile("s_waitcnt vmcnt(" #N ")" ::: "memory");         \
    __builtin_amdgcn_sched_barrier(0);                            \
} while (0)

// ---------------- K_shard: 4D levels LSH..15, XCD-sharded hash space --------
// bid = ((levi*NCHUNK + chunk)*8 + s): round-robin dispatch puts all blocks of
// shard s on XCD s; the 4.19 MB table slice stays L2-resident.
// 2-deep asm pipeline with counted vmcnt(16): 32 loads in flight per wave in
// steady state (vs ~4 when the compiler schedules). Stores deferred to the
// end so vmcnt counts stay exact (stores share the counter).
__global__ __launch_bounds__(256, 2)
void k_shard(const float4* __restrict__ x,
             const float2* __restrict__ emb4d,
             uint32_t* __restrict__ ws2, LevelParams lp)
{
    const int bid   = blockIdx.x;
    const int s     = bid & 7;
    const int rest  = bid >> 3;
    const int chunk = rest & (NCHUNK - 1);
    const int levi  = rest >> 8;           // log2(NCHUNK) = 8
    const int lev   = LSH + levi;
    const uint32_t sh = (uint32_t)s;

    const float2* tab4 = emb4d + ((size_t)lev << 22);
    const float R = lp.res[lev], Rt = lp.rest[lev];
    const int pbase = chunk * 1024 + threadIdx.x;
    uint32_t* dst = ws2 + (size_t)(levi * 8 + s) * B_PTS + pbase;

    f32x4 x0 = *reinterpret_cast<const f32x4*>(&x[pbase]);
    f32x4 x1 = *reinterpret_cast<const f32x4*>(&x[pbase + 256]);
    f32x4 x2 = *reinterpret_cast<const f32x4*>(&x[pbase + 512]);
    f32x4 x3 = *reinterpret_cast<const f32x4*>(&x[pbase + 768]);
    // materialize x and drain the compiler's loads BEFORE any asm gather --
    // otherwise the compiler's own conservative vmcnt waits (it can't see our
    // asm loads) would drain the pipeline mid-loop.
    asm volatile("" : "+v"(x0), "+v"(x1), "+v"(x2), "+v"(x3));
    asm volatile("s_waitcnt vmcnt(0)" ::: "memory");

    Gather A, B;
    PtState st;

    st = mk_fast(x0.x, x0.y, x0.z, x0.w, R, Rt);
    issue_g(tab4, st, sh, A);                       // 16 in flight
    st = mk_fast(x1.x, x1.y, x1.z, x1.w, R, Rt);
    issue_g(tab4, st, sh, B);                       // 32 in flight
    VMWAIT(16);                                     // A landed, B in flight
    uint32_t pk0 = consume_g(A);
    st = mk_fast(x2.x, x2.y, x2.z, x2.w, R, Rt);
    issue_g(tab4, st, sh, A);
    VMWAIT(16);                                     // B landed, A' in flight
    uint32_t pk1 = consume_g(B);
    st = mk_fast(x3.x, x3.y, x3.z, x3.w, R, Rt);
    issue_g(tab4, st, sh, B);
    VMWAIT(16);                                     // A' landed
    uint32_t pk2 = consume_g(A);
    VMWAIT(0);                                      // B' landed
    uint32_t pk3 = consume_g(B);

    __builtin_nontemporal_store(pk0, dst);
    __builtin_nontemporal_store(pk1, dst + 256);
    __builtin_nontemporal_store(pk2, dst + 512);
    __builtin_nontemporal_store(pk3, dst + 768);
}

// ---------------- K_final: 3D + 4D levels 0..3 + shard reduce ---------------
// grid.y = 4: block handles levels 4y..4y+3. Even-pair merge on 3D and
// low-4D gathers.
__global__ __launch_bounds__(256)
void k_final(const float4* __restrict__ x,
             const float2* __restrict__ emb4d,
             const float2* __restrict__ emb3d,
             const uint32_t* __restrict__ ws2,
             float* __restrict__ out, float* __restrict__ keep,
             LevelParams lp)
{
    __shared__ float tile[256 * 9];
    const int t    = threadIdx.x;
    const int p    = blockIdx.x * 256 + t;
    const int lev0 = blockIdx.y * 4;

    const float4 xv = x[p];

    #pragma unroll
    for (int l4 = 0; l4 < 4; ++l4) {
        const int lev = lev0 + l4;
        PtState st = mk_fast(xv.x, xv.y, xv.z, xv.w, lp.res[lev], lp.rest[lev]);
        const uint32_t a0 = st.a, a1 = st.a + 1u;
        const bool odd = (a0 & 1u) != 0u;
        const float wx0 = 1.0f - st.w0, wx1 = st.w0;
        const float wy[2] = { 1.0f - st.w1, st.w1 };
        const float wz[2] = { 1.0f - st.w2, st.w2 };
        const float wwv[2] = { 1.0f - st.w3, st.w3 };

        float ex = 0.0f, ey = 0.0f;

        // shard partials for this level (coalesced u32 reads, bf16x2 packed)
        if (lev >= LSH) {
            const int li = lev - LSH;
            #pragma unroll
            for (int s2 = 0; s2 < 8; ++s2) {
                uint32_t w = ws2[(size_t)(li * 8 + s2) * B_PTS + p];
                ex += __uint_as_float(w << 16);
                ey += __uint_as_float(w & 0xFFFF0000u);
            }
        }

        // 3D: 4 (j,k) pairs, even-merged (footprint <=256 KB, cache-resident)
        {
            const float2* tab3 = emb3d + ((size_t)lev << 15);
            #pragma unroll
            for (int pp = 0; pp < 4; ++pp) {  // pp bits: 1=j, 0=k
                uint32_t E = (((pp & 2) ? st.t1o : st.t1e) ^
                              ((pp & 1) ? st.t2o : st.t2e)) & MASK3;
                uint32_t h0 = E ^ a0;
                float4 qq = *reinterpret_cast<const float4*>(tab3 + (h0 & ~1u));
                float2 ee = make_float2(0.0f, 0.0f);
                if (odd) ee = tab3[E ^ a1];
                const bool hi = (h0 & 1u) != 0u;
                float c0x = hi ? qq.z : qq.x, c0y = hi ? qq.w : qq.y;
                float c1x = odd ? ee.x : (hi ? qq.x : qq.z);
                float c1y = odd ? ee.y : (hi ? qq.y : qq.w);
                float wp = wy[(pp >> 1) & 1] * wz[pp & 1];
                ex = fmaf(c0x, wp * wx0, fmaf(c1x, wp * wx1, ex));
                ey = fmaf(c0y, wp * wx0, fmaf(c1y, wp * wx1, ey));
            }
        }

        // 4D levels 0..3: even-merged, touched footprints <=22 MB (L3)
        if (lev < LSH) {
            const float2* tab4 = emb4d + ((size_t)lev << 22);
            #pragma unroll
            for (int pp = 0; pp < 8; ++pp) {  // pp bits: 2=j, 1=k, 0=l
                uint32_t E = (((pp & 4) ? st.t1o : st.t1e) ^
                              ((pp & 2) ? st.t2o : st.t2e) ^
                              ((pp & 1) ? st.t3o : st.t3e)) & MASK4;
                uint32_t h0 = E ^ a0;
                float4 qq = *reinterpret_cast<const float4*>(tab4 + (h0 & ~1u));
                float2 ee = make_float2(0.0f, 0.0f);
                if (odd) ee = tab4[E ^ a1];
                const bool hi = (h0 & 1u) != 0u;
                float c0x = hi ? qq.z : qq.x, c0y = hi ? qq.w : qq.y;
                float c1x = odd ? ee.x : (hi ? qq.x : qq.z);
                float c1y = odd ? ee.y : (hi ? qq.y : qq.w);
                float wp = wy[(pp >> 2) & 1] * wz[(pp >> 1) & 1] * wwv[pp & 1];
                ex = fmaf(c0x, wp * wx0, fmaf(c1x, wp * wx1, ex));
                ey = fmaf(c0y, wp * wx0, fmaf(c1y, wp * wx1, ey));
            }
        }

        tile[t * 9 + 2 * l4]     = ex;
        tile[t * 9 + 2 * l4 + 1] = ey;
    }

    __syncthreads();

    // write 8 columns per point (32B chunks)
    float* ob = out + (size_t)blockIdx.x * (256 * 32) + lev0 * 2;
    #pragma unroll
    for (int k = 0; k < 8; ++k) {
        int idx = k * 256 + t;
        int row = idx >> 3, col = idx & 7;
        ob[(size_t)row * 32 + col] = tile[row * 9 + col];
    }

    if (blockIdx.y == 0) {
        bool k4 = (xv.x >= 0.0f) && (xv.x <= 1.0f) &&
                  (xv.y >= 0.0f) && (xv.y <= 1.0f) &&
                  (xv.z >= 0.0f) && (xv.z <= 1.0f) &&
                  (xv.w >= 0.0f) && (xv.w <= 1.0f);
        keep[p] = k4 ? 1.0f : 0.0f;
    }
}

// ---------------- fallback (monolithic) if ws is too small ------------------
__global__ __launch_bounds__(256)
void embed_all(const float4* __restrict__ x,
               const float2* __restrict__ emb4d,
               const float2* __restrict__ emb3d,
               float* __restrict__ out,
               float* __restrict__ keep,
               LevelParams lp)
{
    __shared__ float tile[16 * 33];
    const int t = threadIdx.x;
    const int pl = t & 15;
    const int lev = t >> 4;
    const int pbase = blockIdx.x * 16;

    const float4 xv = x[pbase + pl];
    PtState st = mk_fast(xv.x, xv.y, xv.z, xv.w, lp.res[lev], lp.rest[lev]);
    const uint32_t a0 = st.a, a1 = st.a + 1u;
    const float wx[2] = { 1.0f - st.w0, st.w0 };
    const float wy[2] = { 1.0f - st.w1, st.w1 };
    const float wz[2] = { 1.0f - st.w2, st.w2 };
    const float wwv[2] = { 1.0f - st.w3, st.w3 };
    float ex = 0.0f, ey = 0.0f;

    const float2* tab4 = emb4d + ((size_t)lev << 22);
    #pragma unroll
    for (int c = 0; c < 16; ++c) {
        uint32_t E = ((c & 4) ? st.t1o : st.t1e) ^ ((c & 2) ? st.t2o : st.t2e) ^
                     ((c & 1) ? st.t3o : st.t3e);
        uint32_t h = (E ^ ((c & 8) ? a1 : a0)) & MASK4;
        float wt = wx[(c >> 3) & 1] * wy[(c >> 2) & 1] *
                   wz[(c >> 1) & 1] * wwv[c & 1];
        float2 v = tab4[h];
        ex = fmaf(v.x, wt, ex);
        ey = fmaf(v.y, wt, ey);
    }
    const float2* tab3 = emb3d + ((size_t)lev << 15);
    #pragma unroll
    for (int c = 0; c < 8; ++c) {
        uint32_t E = ((c & 2) ? st.t1o : st.t1e) ^ ((c & 1) ? st.t2o : st.t2e);
        uint32_t h = (E ^ ((c & 4) ? a1 : a0)) & MASK3;
        float wt = wx[(c >> 2) & 1] * wy[(c >> 1) & 1] * wz[c & 1];
        float2 v = tab3[h];
        ex = fmaf(v.x, wt, ex);
        ey = fmaf(v.y, wt, ey);
    }

    tile[pl * 33 + 2 * lev]     = ex;
    tile[pl * 33 + 2 * lev + 1] = ey;
    __syncthreads();
    {
        int pw = t >> 4;
        int cw = (2 * t) & 31;
        float2 v = make_float2(tile[pw * 33 + cw], tile[pw * 33 + cw + 1]);
        *reinterpret_cast<float2*>(out + (size_t)pbase * 32 + 2 * t) = v;
    }
    if (t < 16) {
        const float4 xk = x[pbase + t];
        bool k4 = (xk.x >= 0.0f) && (xk.x <= 1.0f) &&
                  (xk.y >= 0.0f) && (xk.y <= 1.0f) &&
                  (xk.z >= 0.0f) && (xk.z <= 1.0f) &&
                  (xk.w >= 0.0f) && (xk.w <= 1.0f);
        keep[pbase + t] = k4 ? 1.0f : 0.0f;
    }
}

extern "C" void kernel_launch(void* const* d_in, const int* in_sizes, int n_in,
                              void* d_out, int out_size, void* d_ws, size_t ws_size,
                              hipStream_t stream)
{
    const float4* x     = (const float4*)d_in[0];
    const float2* emb4d = (const float2*)d_in[1];
    const float2* emb3d = (const float2*)d_in[2];
    float* out  = (float*)d_out;
    float* keep = out + (size_t)B_PTS * 32;

    // Replicate numpy's double-precision level-resolution computation exactly.
    LevelParams lp;
    const double b  = exp((log(512.0) - log(16.0)) / 15.0);
    const double bt = exp((log(32.0)  - log(2.0))  / 15.0);
    for (int i = 0; i < NLEV; ++i) {
        lp.res[i]  = (float)floor(16.0 * pow(b,  (double)i));
        lp.rest[i] = (float)floor(2.0  * pow(bt, (double)i));
    }

    const size_t ws2_bytes = (size_t)NSHL * 8 * B_PTS * 4;      // ~101 MB

    if (ws_size >= ws2_bytes && d_ws != nullptr) {
        uint32_t* ws2 = (uint32_t*)d_ws;
        k_shard<<<NSHL * NCHUNK * 8,    256, 0, stream>>>(x, emb4d, ws2, lp);
        k_final<<<dim3(B_PTS / 256, 4), 256, 0, stream>>>(x, emb4d, emb3d,
                                                          ws2, out, keep, lp);
    } else {
        embed_all<<<B_PTS / 16, 256, 0, stream>>>(x, emb4d, emb3d, out, keep, lp);
    }
}